// Round 1
// 71.316 us; speedup vs baseline: 1.0374x; 1.0374x over previous
//
#include <hip/hip_runtime.h>
#include <math.h>

#define B 64
#define F 128
#define T 64
#define D 256
#define TC 16            // t-chunk width per block
#define NC (T / TC)      // 4 chunks -> grid = 256 blocks = 1/CU

// One fused kernel. Block (b, c) owns t in [c*TC, c*TC+TC).
// Thread layout: fg = tid>>4 (f-group 0..15), lt = tid&15 (t within chunk).
// Each thread handles f = fg + 16*i, i=0..7  (8 sigmoids, vatt kept in regs).
__global__ __launch_bounds__(256) void fused_kernel(
    const float* __restrict__ x,
    const float* __restrict__ wconv, const float* __restrict__ bconv,
    const float* __restrict__ w1, const float* __restrict__ b1,
    const float* __restrict__ w2, const float* __restrict__ b2,
    float* __restrict__ out1, float* __restrict__ out2) {

    __shared__ float b1_s[F * (TC + 1)];   // [f][lt], +1 pad breaks stride-16 bank aliasing
    __shared__ float A_s[TC], C_s[TC], P_s[TC], Q_s[TC];
    __shared__ float s0red[4 * TC], s1red[4 * TC];
    __shared__ float s0_s[TC], s1_s[TC], tatt_s[TC];

    const int blk = blockIdx.x;
    const int b  = blk & (B - 1);   // stride-64 ≡ 0 mod 8: all 4 chunks of b on same XCD
    const int c  = blk >> 6;        // t-chunk id 0..3
    const int t0 = c * TC;
    const int tid  = threadIdx.x;
    const int w    = tid >> 6;      // wave 0..3
    const int lane = tid & 63;
    const int fg   = tid >> 4;      // 0..15
    const int lt   = tid & (TC - 1);

    // ---- issue the 8 x-loads first: independent HBM loads in flight over phase 0 ----
    const float* xb = x + b * F * T + t0 + lt;
    float xv[8];
    #pragma unroll
    for (int i = 0; i < 8; ++i) xv[i] = xb[(fg + 16 * i) * T];

    // ---- stage b1 chunk [TC x F] -> b1_s transposed [f][lt] (coalesced reads) ----
    #pragma unroll
    for (int k = 0; k < (TC * F) / 256; ++k) {
        const int lin = tid + 256 * k;
        const int tl  = lin >> 7;        // / F
        const int f   = lin & (F - 1);
        b1_s[f * (TC + 1) + tl] = b1[(t0 + tl) * F + f];
    }

    // ---- phase 0: in-block coefficients for this chunk's 16 t's ----
    // A[t]=dot(wconv[t],w1[t]) C[t]=dot(bconv[t],w1[t]) P[t]=dot(wconv[t],w2) Q[t]=dot(bconv[t],w2)
    {
        const float4 w2v = *reinterpret_cast<const float4*>(w2 + lane * 4);
        #pragma unroll
        for (int j = 0; j < 4; ++j) {
            const int tl = w * 4 + j;                    // wave w covers 4 t's
            const int base = (t0 + tl) * D + lane * 4;
            const float4 wc  = *reinterpret_cast<const float4*>(wconv + base);
            const float4 bc  = *reinterpret_cast<const float4*>(bconv + base);
            const float4 w1v = *reinterpret_cast<const float4*>(w1 + base);
            float a  = wc.x*w1v.x + wc.y*w1v.y + wc.z*w1v.z + wc.w*w1v.w;
            float cc = bc.x*w1v.x + bc.y*w1v.y + bc.z*w1v.z + bc.w*w1v.w;
            float p  = wc.x*w2v.x + wc.y*w2v.y + wc.z*w2v.z + wc.w*w2v.w;
            float q  = bc.x*w2v.x + bc.y*w2v.y + bc.z*w2v.z + bc.w*w2v.w;
            #pragma unroll
            for (int off = 32; off > 0; off >>= 1) {     // wave64 reduce
                a  += __shfl_down(a, off);
                cc += __shfl_down(cc, off);
                p  += __shfl_down(p, off);
                q  += __shfl_down(q, off);
            }
            if (lane == 0) { A_s[tl] = a; C_s[tl] = cc; P_s[tl] = p; Q_s[tl] = q; }
        }
    }
    __syncthreads();

    // ---- phase 1: vatt (in regs) + per-thread partial S0/S1 ----
    const float At = A_s[lt], Ct = C_s[lt];
    float vreg[8];
    float s0 = 0.f, s1 = 0.f;
    #pragma unroll
    for (int i = 0; i < 8; ++i) {
        const int f = fg + 16 * i;
        const float z = xv[i] * At + Ct + b1_s[f * (TC + 1) + lt];
        const float v = 1.0f / (1.0f + __expf(-z));
        vreg[i] = v;
        s0 += v;
        s1 += v * xv[i];
    }
    // in-wave reduce across this wave's 4 f-groups (same lt at lane, lane+16, +32, +48)
    s0 += __shfl_down(s0, 32); s1 += __shfl_down(s1, 32);
    s0 += __shfl_down(s0, 16); s1 += __shfl_down(s1, 16);
    if (lane < TC) { s0red[w * TC + lane] = s0; s1red[w * TC + lane] = s1; }
    __syncthreads();

    // ---- phase 2: cross-wave reduce + temporal attention for the chunk ----
    if (tid < TC) {
        const float S0 = s0red[tid] + s0red[TC + tid] + s0red[2*TC + tid] + s0red[3*TC + tid];
        const float S1 = s1red[tid] + s1red[TC + tid] + s1red[2*TC + tid] + s1red[3*TC + tid];
        const float z  = S1 * P_s[tid] + S0 * Q_s[tid] + b2[t0 + tid];
        s0_s[tid] = S0;
        s1_s[tid] = S1;
        tatt_s[tid] = 1.0f / (1.0f + __expf(-z));
    }
    __syncthreads();

    // ---- phase 3a: this chunk's out1 contribution, d = tid (wconv/bconv rows L2-hot) ----
    float acc = 0.f;
    #pragma unroll
    for (int j = 0; j < TC; ++j) {
        const int t = t0 + j;
        acc += tatt_s[j] * (wconv[t * D + tid] * s1_s[j] + bconv[t * D + tid] * s0_s[j]);
    }
    atomicAdd(out1 + b * D + tid, acc);   // 4-way contention, same-XCD L2

    // ---- phase 3b: out2[b,f,t] = vatt * tatt (same addressing as x loads) ----
    float* o2 = out2 + b * F * T + t0 + lt;
    const float ta = tatt_s[lt];
    #pragma unroll
    for (int i = 0; i < 8; ++i) {
        o2[(fg + 16 * i) * T] = vreg[i] * ta;
    }
}

extern "C" void kernel_launch(void* const* d_in, const int* in_sizes, int n_in,
                              void* d_out, int out_size, void* d_ws, size_t ws_size,
                              hipStream_t stream) {
    const float* x     = (const float*)d_in[0];
    const float* wconv = (const float*)d_in[1];
    const float* bconv = (const float*)d_in[2];
    const float* w1    = (const float*)d_in[3];
    const float* b1    = (const float*)d_in[4];
    const float* w2    = (const float*)d_in[5];
    const float* b2    = (const float*)d_in[6];
    float* out = (float*)d_out;   // [B,D] then [B,F,T]

    // zero out1 for the cross-chunk atomic accumulation (capturable memset node)
    hipMemsetAsync(out, 0, B * D * sizeof(float), stream);
    fused_kernel<<<B * NC, 256, 0, stream>>>(x, wconv, bconv, w1, b1, w2, b2,
                                             out, out + B * D);
}